// Round 4
// baseline (137.887 us; speedup 1.0000x reference)
//
#include <hip/hip_runtime.h>
#include <math.h>

#define NN   2048
#define KZ   20
#define IFZ  128
#define AHZ  4
#define AFZ  32
#define ROWS (NN*KZ)           // 40960
#define TWO_KZ (2*KZ)          // 40

typedef __attribute__((ext_vector_type(8))) short short8v;   // 8 bf16 = 4 VGPR
typedef __attribute__((ext_vector_type(4))) float f32x4;     // MFMA acc

__device__ __forceinline__ float blo(unsigned int u) {      // low bf16 of packed pair
    union { unsigned int i; float f; } x; x.i = u << 16; return x.f;
}
__device__ __forceinline__ float bhi(unsigned int u) {      // high bf16 of packed pair
    union { unsigned int i; float f; } x; x.i = u & 0xffff0000u; return x.f;
}
__device__ __forceinline__ unsigned short f2b(float f) {
    union { float f; unsigned int i; } x; x.f = f;
    unsigned int r = x.i + 0x7fffu + ((x.i >> 16) & 1u);
    return (unsigned short)(r >> 16);
}

// ---------------------------------------------------------------------------
// prep_x: x (f32, ROWS x 128) -> xb (bf16). 8 elems/thread.
// ---------------------------------------------------------------------------
__global__ __launch_bounds__(256) void prep_x(const float* __restrict__ x,
                                              unsigned short* __restrict__ xb)
{
    const int gid = blockIdx.x * 256 + threadIdx.x;        // 0 .. ROWS*IFZ/8
    const float4* src = (const float4*)x;
    float4 v0 = src[gid * 2];
    float4 v1 = src[gid * 2 + 1];
    uint4 o;
    o.x = (unsigned)f2b(v0.x) | ((unsigned)f2b(v0.y) << 16);
    o.y = (unsigned)f2b(v0.z) | ((unsigned)f2b(v0.w) << 16);
    o.z = (unsigned)f2b(v1.x) | ((unsigned)f2b(v1.y) << 16);
    o.w = (unsigned)f2b(v1.z) | ((unsigned)f2b(v1.w) << 16);
    ((uint4*)xb)[gid] = o;
}

// ---------------------------------------------------------------------------
// wtrans: build transposed bf16 weights.
// ---------------------------------------------------------------------------
__global__ __launch_bounds__(256) void wtrans(
    const float* __restrict__ Wq, const float* __restrict__ Wk,
    const float* __restrict__ Wv, const float* __restrict__ Wg,
    const float* __restrict__ Wback,
    unsigned short* __restrict__ Wt, unsigned short* __restrict__ Wbt)
{
    const int gid = blockIdx.x * 256 + threadIdx.x;
    if (gid < 512 * 128) {
        const int n = gid >> 7, k = gid & 127;
        const float* W; int c;
        if      (n < 128) { W = Wq; c = n; }
        else if (n < 256) { W = Wk; c = n - 128; }
        else if (n < 384) { W = Wv; c = n - 256; }
        else              { W = Wg; c = n - 384; }
        Wt[gid] = f2b(W[k * 128 + c]);
    } else {
        const int g2 = gid - 512 * 128;
        const int n = g2 >> 7, k = g2 & 127;
        Wbt[g2] = f2b(Wback[k * 128 + n]);
    }
}

// ---------------------------------------------------------------------------
// bproj: b = xb @ Wb  (ROWS x 4), f32 accum from bf16 x. One row per thread.
// ---------------------------------------------------------------------------
__global__ __launch_bounds__(256) void bproj(const unsigned short* __restrict__ xb,
                                             const float* __restrict__ Wb,
                                             float* __restrict__ bbuf)
{
    const int row = blockIdx.x * 256 + threadIdx.x;        // 0 .. ROWS
    const unsigned* xv = (const unsigned*)xb + (size_t)row * 64;
    const float4* wv = (const float4*)Wb;                  // Wb[k][0..3]
    float4 acc = make_float4(0.f, 0.f, 0.f, 0.f);
    #pragma unroll
    for (int u = 0; u < 64; ++u) {
        const unsigned xu = xv[u];
        const float x0 = blo(xu), x1 = bhi(xu);
        const float4 w0 = wv[2*u], w1 = wv[2*u+1];
        acc.x += x0*w0.x + x1*w1.x;
        acc.y += x0*w0.y + x1*w1.y;
        acc.z += x0*w0.z + x1*w1.z;
        acc.w += x0*w0.w + x1*w1.w;
    }
    ((float4*)bbuf)[row] = acc;
}

// ---------------------------------------------------------------------------
// proj_gemm: [q|k|v|g] = xb @ Wt^T, MFMA 16x16x32 bf16, no LDS.
// ---------------------------------------------------------------------------
__global__ __launch_bounds__(256) void proj_gemm(
    const unsigned short* __restrict__ xb, const unsigned short* __restrict__ Wt,
    const float* __restrict__ bg,
    unsigned short* __restrict__ qb, unsigned short* __restrict__ kb,
    unsigned short* __restrict__ vb, unsigned short* __restrict__ gb)
{
    const int row0 = blockIdx.x * 128;
    const int col0 = blockIdx.y * 128;      // buffer select
    const int wid  = threadIdx.x >> 6;
    const int lane = threadIdx.x & 63;
    const int wm = wid >> 1, wn = wid & 1;
    const int l15 = lane & 15, lg = lane >> 4;

    f32x4 acc[4][4];
    #pragma unroll
    for (int i = 0; i < 4; ++i)
        #pragma unroll
        for (int j = 0; j < 4; ++j) acc[i][j] = (f32x4){0.f,0.f,0.f,0.f};

    const unsigned short* Ab = xb + ((size_t)(row0 + wm*64 + l15)) * IFZ + lg*8;
    const unsigned short* Bb = Wt + ((size_t)(col0 + wn*64 + l15)) * IFZ + lg*8;

    #pragma unroll
    for (int ks = 0; ks < 4; ++ks) {
        short8v a[4], b[4];
        #pragma unroll
        for (int f = 0; f < 4; ++f) {
            a[f] = *((const short8v*)(Ab + (size_t)f*16*IFZ + ks*32));
            b[f] = *((const short8v*)(Bb + (size_t)f*16*IFZ + ks*32));
        }
        #pragma unroll
        for (int fm = 0; fm < 4; ++fm)
            #pragma unroll
            for (int fn = 0; fn < 4; ++fn)
                acc[fm][fn] = __builtin_amdgcn_mfma_f32_16x16x32_bf16(
                    a[fm], b[fn], acc[fm][fn], 0, 0, 0);
    }

    unsigned short* ob;
    switch (blockIdx.y) { case 0: ob = qb; break; case 1: ob = kb; break;
                          case 2: ob = vb; break; default: ob = gb; break; }
    const bool gate = (blockIdx.y == 3);

    #pragma unroll
    for (int fm = 0; fm < 4; ++fm)
        #pragma unroll
        for (int fn = 0; fn < 4; ++fn)
            #pragma unroll
            for (int j = 0; j < 4; ++j) {
                const int row = row0 + wm*64 + fm*16 + lg*4 + j;
                const int cl  = wn*64 + fn*16 + l15;          // 0..127
                float v = acc[fm][fn][j];
                if (gate) v = 1.f / (1.f + __expf(-(v + bg[cl])));
                ob[(size_t)row * IFZ + cl] = f2b(v);
            }
}

// ---------------------------------------------------------------------------
// attn v3: one block per node, register-reuse mapping.
//  LDS: qsu/ksu [kk][a][20] uints (16B-aligned per-head, stride 80 uints/row),
//       sc [80 rows][41], bias, edges. 26.4 KB -> 6 blocks/CU.
//  Phase 1: thread owns (kk,a) [3 threads split 40 keys]; q unpacked to f32
//           regs once; self-k via 4x ds_read_b128 (broadcast across kk);
//           neighbor-k via 4x global uint4.
//  Phase 3: thread owns column-pair; self-V in 20 regs reused across 5 kk.
// ---------------------------------------------------------------------------
__global__ __launch_bounds__(256) void attn_kernel(
    const unsigned short* __restrict__ qb, const unsigned short* __restrict__ kb,
    const unsigned short* __restrict__ vb, const unsigned short* __restrict__ gb,
    const float* __restrict__ bbuf, const int* __restrict__ edge,
    unsigned short* __restrict__ obuf)
{
    const int n   = blockIdx.x;
    const int tid = threadIdx.x;

    __shared__ unsigned qsu[KZ*80];      // [kk][a][20] packed bf16 pairs
    __shared__ unsigned ksu[KZ*80];
    __shared__ float    sc[KZ*AHZ*41];   // row p=kk*4+a, stride 41
    __shared__ float    bs[KZ*AHZ];
    __shared__ int      es[KZ];
    __shared__ unsigned eb16[KZ];        // e * KZ*IFZ (short-element base)

    const size_t base  = (size_t)n * (KZ*IFZ);
    const unsigned base2 = (unsigned)n * (KZ*64);   // uint-element base

    {
        const uint4* qsrc = (const uint4*)(qb + base);
        const uint4* ksrc = (const uint4*)(kb + base);
        for (int i = tid; i < KZ*16; i += 256) {
            const int r = i >> 4, u4 = i & 15;
            const int d = r*80 + (u4 >> 2)*20 + (u4 & 3)*4;
            *(uint4*)&qsu[d] = qsrc[i];
            *(uint4*)&ksu[d] = ksrc[i];
        }
    }
    if (tid < KZ) {
        const int e = edge[n*KZ + tid];
        es[tid]   = e;
        eb16[tid] = (unsigned)e * (KZ*IFZ);
    }
    if (tid < KZ*AHZ)  bs[tid] = bbuf[(size_t)n*(KZ*AHZ) + tid];
    __syncthreads();

    const float rscale = 0.17677669529663687f;  // 1/sqrt(32)

    // ---- Phase 1: scores. thread t<240: pair p=t/3 (kk=p>>2, a=p&3), part r3.
    if (tid < 240) {
        const int p  = tid / 3, r3 = tid - p*3;
        const int kk = p >> 2, a = p & 3;

        // q row -> f32 registers (unpack once)
        unsigned qu_[16];
        {
            const uint4 q0 = *(const uint4*)&qsu[kk*80 + a*20 + 0];
            const uint4 q1 = *(const uint4*)&qsu[kk*80 + a*20 + 4];
            const uint4 q2 = *(const uint4*)&qsu[kk*80 + a*20 + 8];
            const uint4 q3 = *(const uint4*)&qsu[kk*80 + a*20 + 12];
            qu_[0]=q0.x; qu_[1]=q0.y; qu_[2]=q0.z; qu_[3]=q0.w;
            qu_[4]=q1.x; qu_[5]=q1.y; qu_[6]=q1.z; qu_[7]=q1.w;
            qu_[8]=q2.x; qu_[9]=q2.y; qu_[10]=q2.z; qu_[11]=q2.w;
            qu_[12]=q3.x; qu_[13]=q3.y; qu_[14]=q3.z; qu_[15]=q3.w;
        }
        float qf[32];
        #pragma unroll
        for (int c = 0; c < 16; ++c) { qf[2*c] = blo(qu_[c]); qf[2*c+1] = bhi(qu_[c]); }

        // self keys
        for (int j = r3; j < KZ; j += 3) {
            const int kbse = j*80 + a*20;
            const uint4 k0 = *(const uint4*)&ksu[kbse + 0];
            const uint4 k1 = *(const uint4*)&ksu[kbse + 4];
            const uint4 k2 = *(const uint4*)&ksu[kbse + 8];
            const uint4 k3 = *(const uint4*)&ksu[kbse + 12];
            unsigned ku_[16];
            ku_[0]=k0.x; ku_[1]=k0.y; ku_[2]=k0.z; ku_[3]=k0.w;
            ku_[4]=k1.x; ku_[5]=k1.y; ku_[6]=k1.z; ku_[7]=k1.w;
            ku_[8]=k2.x; ku_[9]=k2.y; ku_[10]=k2.z; ku_[11]=k2.w;
            ku_[12]=k3.x; ku_[13]=k3.y; ku_[14]=k3.z; ku_[15]=k3.w;
            float s = 0.f;
            #pragma unroll
            for (int c = 0; c < 16; ++c)
                s += qf[2*c]*blo(ku_[c]) + qf[2*c+1]*bhi(ku_[c]);
            sc[p*41 + j] = s*rscale + bs[j*AHZ + a];
        }

        // neighbor keys
        {
            const unsigned ebase = eb16[kk];
            const int e = es[kk];
            for (int jj = r3; jj < KZ; jj += 3) {
                const uint4* kp = (const uint4*)(kb + (size_t)(ebase + jj*IFZ + a*AFZ));
                float s = 0.f;
                #pragma unroll
                for (int c8 = 0; c8 < 4; ++c8) {
                    const uint4 kv = kp[c8];
                    s += qf[8*c8+0]*blo(kv.x) + qf[8*c8+1]*bhi(kv.x)
                       + qf[8*c8+2]*blo(kv.y) + qf[8*c8+3]*bhi(kv.y)
                       + qf[8*c8+4]*blo(kv.z) + qf[8*c8+5]*bhi(kv.z)
                       + qf[8*c8+6]*blo(kv.w) + qf[8*c8+7]*bhi(kv.w);
                }
                sc[p*41 + KZ + jj] = s*rscale + bbuf[(unsigned)e*(KZ*AHZ) + jj*AHZ + a];
            }
        }
    }
    __syncthreads();

    // ---- Phase 2: softmax over the 40 keys, one thread per (kk,a) row.
    if (tid < KZ*AHZ) {
        float* row = &sc[tid*41];
        float m = row[0];
        #pragma unroll
        for (int j = 1; j < TWO_KZ; ++j) m = fmaxf(m, row[j]);
        float ssum = 0.f;
        #pragma unroll
        for (int j = 0; j < TWO_KZ; ++j) { const float e = __expf(row[j]-m); row[j] = e; ssum += e; }
        const float inv = 1.f/ssum;
        #pragma unroll
        for (int j = 0; j < TWO_KZ; ++j) row[j] *= inv;
    }
    __syncthreads();

    // ---- Phase 3: context + gate. thread: c2 = tid&63, kk group = tid>>6 (5 kk).
    {
        const int c2  = tid & 63;          // column pair {2c2, 2c2+1}
        const int kkg = tid >> 6;          // 0..3
        const int a   = c2 >> 4;
        const unsigned* vbu = (const unsigned*)vb;
        const unsigned* gbu = (const unsigned*)gb;
        unsigned* obu = (unsigned*)obuf;

        // self-V column pair -> registers (reused for 5 kk)
        unsigned vs_[KZ];
        #pragma unroll
        for (int j = 0; j < KZ; ++j) vs_[j] = vbu[base2 + j*64 + c2];

        #pragma unroll
        for (int i = 0; i < 5; ++i) {
            const int kk = kkg*5 + i;
            const float* wrow = &sc[(kk*4 + a)*41];
            float acc0 = 0.f, acc1 = 0.f;
            #pragma unroll
            for (int j = 0; j < KZ; ++j) {
                const float w = wrow[j];
                acc0 += w*blo(vs_[j]); acc1 += w*bhi(vs_[j]);
            }
            const unsigned eb2 = eb16[kk] >> 1;   // uint-element base of neighbor
            for (int j = 0; j < KZ; ++j) {
                const unsigned u = vbu[eb2 + j*64 + c2];
                const float w = wrow[KZ + j];
                acc0 += w*blo(u); acc1 += w*bhi(u);
            }
            const unsigned gu = gbu[base2 + kk*64 + c2];
            const float o0 = acc0 * blo(gu);
            const float o1 = acc1 * bhi(gu);
            obu[base2 + kk*64 + c2] = (unsigned)f2b(o0) | ((unsigned)f2b(o1) << 16);
        }
    }
}

// ---------------------------------------------------------------------------
// back_ln: y = ob @ Wbt^T + bback + sqrt2*x, then LayerNorm. MFMA, BM=64.
// ---------------------------------------------------------------------------
__global__ __launch_bounds__(256) void back_ln_kernel(
    const unsigned short* __restrict__ ob, const unsigned short* __restrict__ Wbt,
    const float* __restrict__ x, const float* __restrict__ bback,
    const float* __restrict__ gamma, const float* __restrict__ beta,
    float* __restrict__ out)
{
    __shared__ float ys[64][132];
    __shared__ float st[64][2];
    const int row0 = blockIdx.x * 64;
    const int tid  = threadIdx.x;
    const int wid  = tid >> 6;
    const int lane = tid & 63;
    const int wm = wid >> 1, wn = wid & 1;
    const int l15 = lane & 15, lg = lane >> 4;

    f32x4 acc[2][4];
    #pragma unroll
    for (int i = 0; i < 2; ++i)
        #pragma unroll
        for (int j = 0; j < 4; ++j) acc[i][j] = (f32x4){0.f,0.f,0.f,0.f};

    const unsigned short* Ab = ob  + ((size_t)(row0 + wm*32 + l15)) * IFZ + lg*8;
    const unsigned short* Bb = Wbt + ((size_t)(wn*64 + l15)) * IFZ + lg*8;

    #pragma unroll
    for (int ksI = 0; ksI < 4; ++ksI) {
        short8v a[2], b[4];
        #pragma unroll
        for (int f = 0; f < 2; ++f) a[f] = *((const short8v*)(Ab + (size_t)f*16*IFZ + ksI*32));
        #pragma unroll
        for (int f = 0; f < 4; ++f) b[f] = *((const short8v*)(Bb + (size_t)f*16*IFZ + ksI*32));
        #pragma unroll
        for (int fm = 0; fm < 2; ++fm)
            #pragma unroll
            for (int fn = 0; fn < 4; ++fn)
                acc[fm][fn] = __builtin_amdgcn_mfma_f32_16x16x32_bf16(
                    a[fm], b[fn], acc[fm][fn], 0, 0, 0);
    }

    const float SQ2 = 1.4142135623730951f;
    #pragma unroll
    for (int fm = 0; fm < 2; ++fm)
        #pragma unroll
        for (int fn = 0; fn < 4; ++fn)
            #pragma unroll
            for (int j = 0; j < 4; ++j) {
                const int rl  = wm*32 + fm*16 + lg*4 + j;
                const int col = wn*64 + fn*16 + l15;
                ys[rl][col] = acc[fm][fn][j] + bback[col]
                            + SQ2 * x[((size_t)(row0 + rl)) * IFZ + col];
            }
    __syncthreads();

    {
        const int row = tid >> 2, q = tid & 3;
        float s1 = 0.f, s2 = 0.f;
        #pragma unroll
        for (int i = 0; i < 32; ++i) {
            const float yv = ys[row][q*32 + i];
            s1 += yv; s2 += yv*yv;
        }
        s1 += __shfl_xor(s1, 1); s2 += __shfl_xor(s2, 1);
        s1 += __shfl_xor(s1, 2); s2 += __shfl_xor(s2, 2);
        if (q == 0) {
            const float mean = s1 * (1.f/IFZ);
            const float var  = s2 * (1.f/IFZ) - mean*mean;
            st[row][0] = mean;
            st[row][1] = rsqrtf(var + 1e-5f);
        }
    }
    __syncthreads();

    {
        const int row = tid >> 2, q = tid & 3;
        const float mean = st[row][0], rstd = st[row][1];
        const float4* gmv = (const float4*)(gamma + q*32);
        const float4* btv = (const float4*)(beta  + q*32);
        float4* ov = (float4*)(out + ((size_t)(row0 + row)) * IFZ + q*32);
        #pragma unroll
        for (int i8 = 0; i8 < 8; ++i8) {
            const float4 g4 = gmv[i8], b4 = btv[i8];
            const float4 yv = *(const float4*)&ys[row][q*32 + i8*4];
            float4 r;
            r.x = g4.x*(yv.x-mean)*rstd + b4.x;
            r.y = g4.y*(yv.y-mean)*rstd + b4.y;
            r.z = g4.z*(yv.z-mean)*rstd + b4.z;
            r.w = g4.w*(yv.w-mean)*rstd + b4.w;
            ov[i8] = r;
        }
    }
}

// ---------------------------------------------------------------------------
extern "C" void kernel_launch(void* const* d_in, const int* in_sizes, int n_in,
                              void* d_out, int out_size, void* d_ws, size_t ws_size,
                              hipStream_t stream) {
    const float* x     = (const float*)d_in[0];
    const int*   edge  = (const int*)  d_in[1];
    const float* Wq    = (const float*)d_in[2];
    const float* Wk    = (const float*)d_in[3];
    const float* Wv    = (const float*)d_in[4];
    const float* Wb    = (const float*)d_in[5];
    const float* Wg    = (const float*)d_in[6];
    const float* bg    = (const float*)d_in[7];
    const float* Wback = (const float*)d_in[8];
    const float* bback = (const float*)d_in[9];
    const float* gamma = (const float*)d_in[10];
    const float* beta  = (const float*)d_in[11];
    float* out = (float*)d_out;

    const size_t RE = (size_t)ROWS * IFZ;   // 5,242,880 elements
    unsigned short* qb  = (unsigned short*)d_ws;
    unsigned short* kb  = qb + RE;
    unsigned short* vb  = kb + RE;
    unsigned short* gb  = vb + RE;
    unsigned short* obuf= gb + RE;
    unsigned short* xb  = obuf + RE;
    unsigned short* Wt  = xb + RE;          // 512*128
    unsigned short* Wbt = Wt + 512*128;     // 128*128
    float*          bbuf= (float*)(Wbt + 128*128);   // ROWS*4 f32
    // total ws use ~63.7 MB

    prep_x     <<<ROWS*IFZ/(256*8), 256, 0, stream>>>(x, xb);
    wtrans     <<<(512*128 + 128*128)/256, 256, 0, stream>>>(Wq, Wk, Wv, Wg, Wback, Wt, Wbt);
    bproj      <<<ROWS/256, 256, 0, stream>>>(xb, Wb, bbuf);
    proj_gemm  <<<dim3(ROWS/128, 4), 256, 0, stream>>>(xb, Wt, bg, qb, kb, vb, gb);
    attn_kernel<<<NN, 256, 0, stream>>>(qb, kb, vb, gb, bbuf, edge, obuf);
    back_ln_kernel<<<ROWS/64, 256, 0, stream>>>(obuf, Wbt, x, bback, gamma, beta, out);
}